// Round 11
// baseline (971.435 us; speedup 1.0000x reference)
//
#include <hip/hip_runtime.h>
#include <math.h>

typedef __attribute__((ext_vector_type(8))) _Float16 f16x8;
typedef __attribute__((ext_vector_type(4))) _Float16 f16x4;
typedef __attribute__((ext_vector_type(2))) _Float16 f16x2;
typedef __attribute__((ext_vector_type(4))) float f32x4;

static __device__ __forceinline__ int getidx(const int* __restrict__ ei, int mode, long long pos) {
  return mode ? ei[2 * pos] : ei[pos];
}

__global__ void detect_kernel(const int* __restrict__ ei, int* __restrict__ mode) {
  int lane = threadIdx.x & 63;
  int v = ei[2 * lane + 1] | ei[2 * lane + 129];
  unsigned long long nz = __ballot(v != 0);
  if (lane == 0) mode[0] = (nz == 0ull) ? 1 : 0;
}

__global__ void zero_kernel(float* __restrict__ p, long long n) {
  long long i = (long long)blockIdx.x * blockDim.x + threadIdx.x;
  if (i < n) p[i] = 0.f;
}

// ---------- f32 -> f16 conversion (4 elems/thread) ----------
__global__ void f32tof16_kernel(const float* __restrict__ in, unsigned short* __restrict__ out,
                                long long n4) {
  long long i = (long long)blockIdx.x * 256 + threadIdx.x;
  if (i >= n4) return;
  float4 v = ((const float4*)in)[i];
  f16x4 h;
  h[0] = (_Float16)v.x; h[1] = (_Float16)v.y; h[2] = (_Float16)v.z; h[3] = (_Float16)v.w;
  ((f16x4*)out)[i] = h;
}

// ---------- pack conv weights to fp16: Wh1cat[256][256]=[Wl1|Wr1], Wh2cat[128][256]=[Wl2;Wr2] ----------
__global__ void w16cat_kernel(const float* __restrict__ Wl1, const float* __restrict__ Wr1,
                              const float* __restrict__ Wl2, const float* __restrict__ Wr2,
                              unsigned short* __restrict__ wh1, unsigned short* __restrict__ wh2) {
  int idx = blockIdx.x * 256 + threadIdx.x;
  if (idx < 65536) {
    int o = idx >> 8, k = idx & 255;
    float v = (k < 128) ? Wl1[o * 128 + k] : Wr1[o * 128 + k - 128];
    _Float16 hv = (_Float16)v;
    wh1[idx] = *(unsigned short*)&hv;
  } else if (idx < 65536 + 32768) {
    int i2 = idx - 65536;
    int o = i2 >> 8, k = i2 & 255;
    float v = (o < 64) ? Wl2[o * 256 + k] : Wr2[(o - 64) * 256 + k];
    _Float16 hv = (_Float16)v;
    wh2[i2] = *(unsigned short*)&hv;
  }
}

// ================= CSR build (counting sort by dst) =================
__global__ void hist_kernel(const int* __restrict__ ei, int* __restrict__ cnt,
                            const int* __restrict__ modep, int E) {
  const int md = modep[0];
  int e = blockIdx.x * 256 + threadIdx.x;
  if (e >= E) return;
  int d = getidx(ei, md, (long long)E + e);
  atomicAdd(&cnt[d], 1);
}

__global__ void scan1_kernel(const int* __restrict__ cnt, int* __restrict__ pre,
                             int* __restrict__ bsum, int N) {
  __shared__ int ws[4];
  int i = blockIdx.x * 256 + threadIdx.x;
  int v = (i < N) ? cnt[i] : 0;
  int lane = threadIdx.x & 63, w = threadIdx.x >> 6;
  int s = v;
#pragma unroll
  for (int o = 1; o < 64; o <<= 1) { int t = __shfl_up(s, o); if (lane >= o) s += t; }
  if (lane == 63) ws[w] = s;
  __syncthreads();
  int off = 0;
  for (int k = 0; k < w; ++k) off += ws[k];
  if (i < N) pre[i] = s + off - v;
  if (threadIdx.x == 255) bsum[blockIdx.x] = s + off;
}

__global__ void scan2_kernel(int* __restrict__ bsum, int nb) {
  __shared__ int ws[4];
  int i = threadIdx.x;
  int v = (i < nb) ? bsum[i] : 0;
  int lane = i & 63, w = i >> 6;
  int s = v;
#pragma unroll
  for (int o = 1; o < 64; o <<= 1) { int t = __shfl_up(s, o); if (lane >= o) s += t; }
  if (lane == 63) ws[w] = s;
  __syncthreads();
  int off = 0;
  for (int k = 0; k < w; ++k) off += ws[k];
  if (i < nb) bsum[i] = s + off - v;
}

__global__ void scan3_kernel(int* __restrict__ rowptr, const int* __restrict__ bsum,
                             int* __restrict__ fill, int N, int E) {
  int i = blockIdx.x * 256 + threadIdx.x;
  if (i < N) {
    int r = rowptr[i] + bsum[blockIdx.x];
    rowptr[i] = r;
    fill[i] = r;
  }
  if (i == 0) rowptr[N] = E;
}

// reorder: ONE packed 16B scattered store per edge: se2[pos] = (src, w, orig, dst)
__global__ void reorder_kernel(const int* __restrict__ ei, const float* __restrict__ ea,
                               int* __restrict__ fill, uint4* __restrict__ se2,
                               const int* __restrict__ modep, int E) {
  const int md = modep[0];
  int e = blockIdx.x * 256 + threadIdx.x;
  if (e >= E) return;
  int s = getidx(ei, md, e);
  int d = getidx(ei, md, (long long)E + e);
  int pos = atomicAdd(&fill[d], 1);
  se2[pos] = make_uint4((unsigned)s, __float_as_uint(ea[e]), (unsigned)e, (unsigned)d);
}

// ---------- CSR aggregation, conv1: fp16 gather, fp32 accum, fp16 store ----------
__global__ void agg1_csr_kernel(const int* __restrict__ rowptr, const uint4* __restrict__ se2,
                                const unsigned short* __restrict__ xh,
                                unsigned short* __restrict__ agg1h, int N) {
  int n = (int)((blockIdx.x * 256 + threadIdx.x) >> 6);
  int lane = threadIdx.x & 63;
  if (n >= N) return;
  int p = rowptr[n], end = rowptr[n + 1];
  float ax = 0.f, ay = 0.f;
  for (; p + 1 < end; p += 2) {
    uint4 e0 = se2[p], e1 = se2[p + 1];
    float w0 = __uint_as_float(e0.y), w1 = __uint_as_float(e1.y);
    f16x2 v0 = *(const f16x2*)&xh[(size_t)e0.x * 128 + lane * 2];
    f16x2 v1 = *(const f16x2*)&xh[(size_t)e1.x * 128 + lane * 2];
    ax += (float)v0[0] * w0 + (float)v1[0] * w1;
    ay += (float)v0[1] * w0 + (float)v1[1] * w1;
  }
  if (p < end) {
    uint4 e0 = se2[p];
    float w0 = __uint_as_float(e0.y);
    f16x2 v0 = *(const f16x2*)&xh[(size_t)e0.x * 128 + lane * 2];
    ax += (float)v0[0] * w0;
    ay += (float)v0[1] * w0;
  }
  f16x2 st; st[0] = (_Float16)ax; st[1] = (_Float16)ay;
  *(f16x2*)&agg1h[(size_t)n * 128 + lane * 2] = st;
}

// ---------- CSR aggregation, conv2: gathers fp16 t rows ----------
__global__ void agg2_csr_kernel(const int* __restrict__ rowptr, const uint4* __restrict__ se2,
                                const unsigned short* __restrict__ th, float* __restrict__ agg2,
                                int N) {
  int n = (int)((blockIdx.x * 256 + threadIdx.x) >> 6);
  int lane = threadIdx.x & 63;
  if (n >= N) return;
  int p = rowptr[n], end = rowptr[n + 1];
  float acc = 0.f;
  for (; p + 1 < end; p += 2) {
    uint4 e0 = se2[p], e1 = se2[p + 1];
    _Float16 t0 = *(const _Float16*)&th[(size_t)e0.x * 64 + lane];
    _Float16 t1 = *(const _Float16*)&th[(size_t)e1.x * 64 + lane];
    acc += (float)t0 * __uint_as_float(e0.y) + (float)t1 * __uint_as_float(e1.y);
  }
  if (p < end) {
    uint4 e0 = se2[p];
    _Float16 t0 = *(const _Float16*)&th[(size_t)e0.x * 64 + lane];
    acc += (float)t0 * __uint_as_float(e0.y);
  }
  agg2[(size_t)n * 64 + lane] += acc;
}

// ================= fallback atomic scatters (fp32 inputs) =================
__global__ void scatter1_kernel(const int* __restrict__ ei, const float* __restrict__ ea,
                                const float* __restrict__ x, float* __restrict__ agg1,
                                const int* __restrict__ modep, int E) {
  const int md = modep[0];
  int e = (int)(((long long)blockIdx.x * 256 + threadIdx.x) >> 6);
  int lane = threadIdx.x & 63;
  if (e >= E) return;
  int s = getidx(ei, md, e);
  int d = getidx(ei, md, (long long)E + e);
  float w = ea[e];
  float2 v = *(const float2*)&x[(size_t)s * 128 + lane * 2];
  float* ap = &agg1[(size_t)d * 128 + lane * 2];
  atomicAdd(ap, v.x * w);
  atomicAdd(ap + 1, v.y * w);
}

__global__ void scatter2_kernel(const int* __restrict__ ei, const float* __restrict__ ea,
                                const float* __restrict__ t, float* __restrict__ agg2,
                                const int* __restrict__ modep, int E) {
  const int md = modep[0];
  int e = (int)(((long long)blockIdx.x * 256 + threadIdx.x) >> 6);
  int lane = threadIdx.x & 63;
  if (e >= E) return;
  int s = getidx(ei, md, e);
  int d = getidx(ei, md, (long long)E + e);
  float w = ea[e];
  atomicAdd(&agg2[(size_t)d * 64 + lane], t[(size_t)s * 64 + lane] * w);
}

// ---------- generic fp32 GEMM (fallback path only) ----------
__global__ void gemm_bt(const float* __restrict__ A1, const float* __restrict__ W1, int K1,
                        const float* __restrict__ A2, const float* __restrict__ W2, int K2,
                        const float* __restrict__ b1, const float* __restrict__ b2,
                        float* __restrict__ C, int NC, int doRelu) {
  __shared__ float As[64][17];
  __shared__ float Ws[64][17];
  int tid = threadIdx.x;
  int tx = tid & 15, ty = tid >> 4;
  int row0 = blockIdx.y * 64, col0 = blockIdx.x * 64;
  float acc[4][4] = {};
  for (int srcsel = 0; srcsel < 2; ++srcsel) {
    const float* A = srcsel ? A2 : A1;
    const float* W = srcsel ? W2 : W1;
    int K = srcsel ? K2 : K1;
    if (!A) continue;
    for (int kb = 0; kb < K; kb += 16) {
#pragma unroll
      for (int i = 0; i < 4; ++i) {
        int idx = tid + 256 * i;
        int r = idx >> 4, k = idx & 15;
        As[r][k] = A[(size_t)(row0 + r) * K + kb + k];
        Ws[r][k] = W[(size_t)(col0 + r) * K + kb + k];
      }
      __syncthreads();
#pragma unroll
      for (int k = 0; k < 16; ++k) {
        float a[4], w[4];
#pragma unroll
        for (int i = 0; i < 4; ++i) a[i] = As[ty * 4 + i][k];
#pragma unroll
        for (int j = 0; j < 4; ++j) w[j] = Ws[tx * 4 + j][k];
#pragma unroll
        for (int i = 0; i < 4; ++i)
#pragma unroll
          for (int j = 0; j < 4; ++j) acc[i][j] += a[i] * w[j];
      }
      __syncthreads();
    }
  }
#pragma unroll
  for (int j = 0; j < 4; ++j) {
    int c = col0 + tx * 4 + j;
    float bias = (b1 ? b1[c] : 0.f) + (b2 ? b2[c] : 0.f);
#pragma unroll
    for (int i = 0; i < 4; ++i) {
      float v = acc[i][j] + bias;
      if (doRelu) v = fmaxf(v, 0.f);
      C[(size_t)(row0 + ty * 4 + i) * NC + c] = v;
    }
  }
}

// ---------- fp16 MFMA GEMM, M-tile 64, 4 waves ----------
template <int MODE, int OTN>
__global__ void __launch_bounds__(256, 2)
gemm16_kernel(const uint4* __restrict__ A0, const uint4* __restrict__ A1, int c0,
              const unsigned short* __restrict__ Wcat,
              const float* __restrict__ b1, const float* __restrict__ b2,
              unsigned short* __restrict__ outH, float* __restrict__ outF) {
  __shared__ uint4 At[64 * 33];   // 33.8 KB
  int tid = threadIdx.x;
  int lane = tid & 63;
  int wv = tid >> 6;
  int l15 = lane & 15, g = lane >> 4;
  int row0 = blockIdx.x * 64;

  f16x8 bfr[OTN][8];
  float biasv[OTN];
#pragma unroll
  for (int ot = 0; ot < OTN; ++ot) {
    int o = wv * (OTN * 16) + ot * 16 + l15;
    if (MODE == 0) biasv[ot] = b1[o] + b2[o];
    else biasv[ot] = (o >= 64) ? (b1[o - 64] + b2[o - 64]) : 0.f;
#pragma unroll
    for (int kb = 0; kb < 8; ++kb)
      bfr[ot][kb] = *(const f16x8*)&Wcat[(size_t)o * 256 + kb * 32 + g * 8];
  }

#pragma unroll
  for (int i = 0; i < 8; ++i) {
    int idx = tid + 256 * i;
    int r = idx >> 5, c = idx & 31;
    uint4 v = (c < c0) ? A0[(size_t)(row0 + r) * c0 + c]
                       : A1[(size_t)(row0 + r) * (32 - c0) + (c - c0)];
    At[r * 33 + c] = v;
  }
  __syncthreads();

#pragma unroll
  for (int est = 0; est < 4; ++est) {
    int rowA = est * 16 + l15;
    f16x8 a[8];
#pragma unroll
    for (int kb = 0; kb < 8; ++kb)
      a[kb] = *(const f16x8*)&At[rowA * 33 + kb * 4 + g];
#pragma unroll
    for (int ot = 0; ot < OTN; ++ot) {
      f32x4 acc = {0.f, 0.f, 0.f, 0.f};
#pragma unroll
      for (int kb = 0; kb < 8; ++kb)
        acc = __builtin_amdgcn_mfma_f32_16x16x32_f16(a[kb], bfr[ot][kb], acc, 0, 0, 0);
      int o = wv * (OTN * 16) + ot * 16 + l15;
#pragma unroll
      for (int r = 0; r < 4; ++r) {
        int row = row0 + est * 16 + g * 4 + r;
        float v = acc[r] + biasv[ot];
        if (MODE == 0) {
          _Float16 hv = (_Float16)fmaxf(v, 0.f);
          outH[(size_t)row * 256 + o] = *(unsigned short*)&hv;
        } else {
          if (o < 64) {
            _Float16 hv = (_Float16)v;
            outH[(size_t)row * 64 + o] = *(unsigned short*)&hv;
          } else {
            outF[(size_t)row * 64 + (o - 64)] = v;
          }
        }
      }
    }
  }
}

// ---------- fc1 ----------
__global__ void __launch_bounds__(256) fc1_kernel(const float* __restrict__ z0,
                                                  const float* __restrict__ Wfc,
                                                  const float* __restrict__ bfc,
                                                  float* __restrict__ z1) {
  __shared__ float Zs[64][260];
  int tid = threadIdx.x;
  int kc = blockIdx.x;
  const size_t kbase = (size_t)kc * 256;
  for (int i = tid; i < 64 * 256; i += 256) {
    int b = i >> 8, k = i & 255;
    Zs[b][k] = fmaxf(z0[(size_t)b * 64000 + kbase + k], 0.f);
  }
  __syncthreads();
  int o = tid >> 2, q = tid & 3;
  float acc[16];
#pragma unroll
  for (int j = 0; j < 16; ++j) acc[j] = 0.f;
  const float* wp = Wfc + (size_t)o * 64000 + kbase;
  for (int k = 0; k < 256; k += 4) {
    float4 w = *(const float4*)&wp[k];
#pragma unroll
    for (int j = 0; j < 16; ++j) {
      float4 z = *(const float4*)&Zs[q * 16 + j][k];
      acc[j] += z.x * w.x + z.y * w.y + z.z * w.z + z.w * w.w;
    }
  }
  float bias = (kc == 0) ? bfc[o] : 0.f;
#pragma unroll
  for (int j = 0; j < 16; ++j)
    atomicAdd(&z1[(q * 16 + j) * 64 + o], acc[j] + bias);
}

// ---------- fc2: z2 packed per node as fp16: [node][0..63] ----------
__global__ void fc2_kernel(const float* __restrict__ z1, const float* __restrict__ Wfc2,
                           const float* __restrict__ bfc2,
                           unsigned short* __restrict__ z2h, int nPerB) {
  __shared__ float z1s[4096];
  __shared__ float Ws[256][65];
  int tid = threadIdx.x;
  for (int i = tid; i < 4096; i += 256) z1s[i] = z1[i];
  int m0 = blockIdx.x * 256;
  for (int i = tid; i < 256 * 64; i += 256) {
    int r = i >> 6, j = i & 63;
    Ws[r][j] = Wfc2[(size_t)(m0 + r) * 64 + j];
  }
  __syncthreads();
  int m = m0 + tid;
  float bias = bfc2[m];
  int ninb = m >> 6, feat = m & 63;
  for (int b = 0; b < 64; ++b) {
    float acc = bias;
#pragma unroll
    for (int j = 0; j < 64; ++j) acc += z1s[b * 64 + j] * Ws[tid][j];
    float v = fmaxf(acc, 0.f);
    _Float16 hv = (_Float16)v;   // RNE
    size_t node = (size_t)b * nPerB + ninb;
    z2h[node * 64 + feat] = *(unsigned short*)&hv;
  }
}

// ---------- decoder: fp16 MFMA, software-pipelined (double-buffered At, reg-staged gather) ----------
// Per tile t: (1) issue t+1 gather loads -> regs G  (2) MFMA on At[cur] while loads fly
// (3) write G -> At[nxt], stage node-ids for t+2    (4) barrier.
__global__ void __launch_bounds__(256, 2)
decoder_kernel(const uint4* __restrict__ se2, const int* __restrict__ ei,
               const unsigned short* __restrict__ z2h,
               const float* __restrict__ Wd1, const float* __restrict__ bd1,
               const float* __restrict__ Wd2, const float* __restrict__ bd2,
               float* __restrict__ obuf, const int* __restrict__ modep,
               int E, int sorted) {
  __shared__ uint4 At[2][128 * 17];  // 2 x 34.8 KB
  __shared__ int nid[2][256];
  __shared__ float red[4][128];
  const int md = modep[0];
  int tid = threadIdx.x;
  int lane = tid & 63;
  int wv = tid >> 6;
  int l15 = lane & 15, g = lane >> 4;
  int ue = tid >> 3, c8 = tid & 7;

  f16x8 bfr[4][4];
  float wd2v[4], bd1v[4];
#pragma unroll
  for (int ot = 0; ot < 4; ++ot) {
    int o = wv * 64 + ot * 16 + l15;
    wd2v[ot] = Wd2[o];
    bd1v[ot] = bd1[o];
#pragma unroll
    for (int kb = 0; kb < 4; ++kb) {
      const float* wp = Wd1 + (size_t)o * 128 + kb * 32 + g * 8;
      f16x8 bh;
#pragma unroll
      for (int q = 0; q < 8; ++q) bh[q] = (_Float16)wp[q];
      bfr[ot][kb] = bh;
    }
  }
  float bd2v = bd2[0];

  int ntiles = E >> 7;
  int tpb = (ntiles + gridDim.x - 1) / gridDim.x;
  int tA = blockIdx.x * tpb;
  int tB = min(tA + tpb, ntiles);
  if (tA >= tB) return;

  // ---- prologue: stage nid for tA (buf 0) and tA+1 (buf 1), gather tile tA into At[0] ----
  {
    long long eb0 = (long long)tA << 7;
    if (sorted) {
      if (tid < 128) {
        uint4 v = se2[eb0 + tid];
        nid[0][tid] = (int)v.x;
        nid[0][128 + tid] = (int)v.w;
        if (tA + 1 < tB) {
          uint4 v1 = se2[eb0 + 128 + tid];
          nid[1][tid] = (int)v1.x;
          nid[1][128 + tid] = (int)v1.w;
        }
      }
    } else {
      long long p = eb0 + (tid & 127);
      nid[0][tid] = getidx(ei, md, (tid < 128) ? p : (long long)E + p);
      if (tA + 1 < tB) {
        long long p1 = p + 128;
        nid[1][tid] = getidx(ei, md, (tid < 128) ? p1 : (long long)E + p1);
      }
    }
    __syncthreads();
#pragma unroll
    for (int pass = 0; pass < 8; ++pass) {
      int u = pass * 32 + ue;
      int node = nid[0][u];
      uint4 v = *((const uint4*)(z2h + (size_t)node * 64) + c8);
      int eRow = u & 127, side = u >> 7;
      At[0][eRow * 17 + side * 8 + c8] = v;
    }
    __syncthreads();
  }

  int cur = 0;
  for (int t = tA; t < tB; ++t) {
    int nxt = cur ^ 1;
    long long ebase = (long long)t << 7;

    // (1) issue next tile's gather loads into registers
    uint4 G0, G1, G2, G3, G4, G5, G6, G7;
    bool havenext = (t + 1 < tB);
    if (havenext) {
      const uint4* zp;
      int node;
      node = nid[nxt][0 * 32 + ue]; zp = (const uint4*)(z2h + (size_t)node * 64); G0 = zp[c8];
      node = nid[nxt][1 * 32 + ue]; zp = (const uint4*)(z2h + (size_t)node * 64); G1 = zp[c8];
      node = nid[nxt][2 * 32 + ue]; zp = (const uint4*)(z2h + (size_t)node * 64); G2 = zp[c8];
      node = nid[nxt][3 * 32 + ue]; zp = (const uint4*)(z2h + (size_t)node * 64); G3 = zp[c8];
      node = nid[nxt][4 * 32 + ue]; zp = (const uint4*)(z2h + (size_t)node * 64); G4 = zp[c8];
      node = nid[nxt][5 * 32 + ue]; zp = (const uint4*)(z2h + (size_t)node * 64); G5 = zp[c8];
      node = nid[nxt][6 * 32 + ue]; zp = (const uint4*)(z2h + (size_t)node * 64); G6 = zp[c8];
      node = nid[nxt][7 * 32 + ue]; zp = (const uint4*)(z2h + (size_t)node * 64); G7 = zp[c8];
    }

    // (2) compute tile t from At[cur] (loads above still in flight)
    const uint4* Ac = &At[cur][0];
    float sacc[8][4];
#pragma unroll
    for (int i = 0; i < 8; ++i)
#pragma unroll
      for (int r = 0; r < 4; ++r) sacc[i][r] = 0.f;

#pragma unroll
    for (int est = 0; est < 8; ++est) {
      int row = est * 16 + l15;
      f16x8 a[4];
#pragma unroll
      for (int kb = 0; kb < 4; ++kb)
        a[kb] = *(const f16x8*)&Ac[row * 17 + kb * 4 + g];
#pragma unroll
      for (int ot = 0; ot < 4; ++ot) {
        f32x4 acc = {0.f, 0.f, 0.f, 0.f};
#pragma unroll
        for (int kb = 0; kb < 4; ++kb)
          acc = __builtin_amdgcn_mfma_f32_16x16x32_f16(a[kb], bfr[ot][kb], acc, 0, 0, 0);
#pragma unroll
        for (int r = 0; r < 4; ++r) {
          float pp = fmaxf(acc[r] + bd1v[ot], 0.f);
          sacc[est][r] += pp * wd2v[ot];     // D: col=l15 (=o), row=g*4+r (=edge)
        }
      }
    }
#pragma unroll
    for (int est = 0; est < 8; ++est)
#pragma unroll
      for (int r = 0; r < 4; ++r) {
        float s = sacc[est][r];
        s += __shfl_xor(s, 1); s += __shfl_xor(s, 2);
        s += __shfl_xor(s, 4); s += __shfl_xor(s, 8);
        sacc[est][r] = s;
      }
    if (l15 == 0) {
#pragma unroll
      for (int est = 0; est < 8; ++est)
#pragma unroll
        for (int r = 0; r < 4; ++r)
          red[wv][est * 16 + g * 4 + r] = sacc[est][r];
    }
    __syncthreads();
    if (tid < 128) {
      float s = red[0][tid] + red[1][tid] + red[2][tid] + red[3][tid] + bd2v;
      obuf[ebase + tid] = 1.f / (1.f + __expf(-s));
    }

    // (3) write prefetched data to At[nxt]; stage node-ids for tile t+2 into nid[cur]
    if (havenext) {
      int base = (ue & 127) * 17 + (ue >> 7) * 8 + c8;   // u=pass*32+ue -> eRow=(u&127), side=u>>7
      // recompute per-pass layout indices (u = pass*32 + ue)
#pragma unroll
      for (int pass = 0; pass < 8; ++pass) {
        int u = pass * 32 + ue;
        int eRow = u & 127, side = u >> 7;
        uint4 v = (pass == 0) ? G0 : (pass == 1) ? G1 : (pass == 2) ? G2 : (pass == 3) ? G3
                : (pass == 4) ? G4 : (pass == 5) ? G5 : (pass == 6) ? G6 : G7;
        At[nxt][eRow * 17 + side * 8 + c8] = v;
      }
      (void)base;
      if (t + 2 < tB) {
        long long eb2 = (long long)(t + 2) << 7;
        if (sorted) {
          if (tid < 128) {
            uint4 v = se2[eb2 + tid];
            nid[cur][tid] = (int)v.x;
            nid[cur][128 + tid] = (int)v.w;
          }
        } else {
          long long p = eb2 + (tid & 127);
          nid[cur][tid] = getidx(ei, md, (tid < 128) ? p : (long long)E + p);
        }
      }
    }
    // (4) make At[nxt]/nid writes visible for next iteration
    __syncthreads();
    cur = nxt;
  }
}

__global__ void permute_out(const float* __restrict__ outsorted, const uint4* __restrict__ se2,
                            float* __restrict__ out, int E) {
  int i = blockIdx.x * 256 + threadIdx.x;
  if (i < E) out[se2[i].z] = outsorted[i];
}

extern "C" void kernel_launch(void* const* d_in, const int* in_sizes, int n_in,
                              void* d_out, int out_size, void* d_ws, size_t ws_size,
                              hipStream_t stream) {
  const float* x    = (const float*)d_in[0];
  const int*   ei   = (const int*)d_in[1];
  const float* ea   = (const float*)d_in[2];
  const float* Wl1  = (const float*)d_in[3];
  const float* bl1  = (const float*)d_in[4];
  const float* Wr1  = (const float*)d_in[5];
  const float* br1  = (const float*)d_in[6];
  const float* Wl2  = (const float*)d_in[7];
  const float* bl2  = (const float*)d_in[8];
  const float* Wr2  = (const float*)d_in[9];
  const float* br2  = (const float*)d_in[10];
  const float* Wfc  = (const float*)d_in[11];
  const float* bfc  = (const float*)d_in[12];
  const float* Wfc2 = (const float*)d_in[13];
  const float* bfc2 = (const float*)d_in[14];
  const float* Wd1  = (const float*)d_in[15];
  const float* bd1  = (const float*)d_in[16];
  const float* Wd2  = (const float*)d_in[17];
  const float* bd2  = (const float*)d_in[18];
  float* out = (float*)d_out;

  const int N = in_sizes[0] / 128;   // 64000
  const int E = in_sizes[2];         // 2048000
  const int NB = (N + 255) / 256;

  float* agg1 = (float*)d_ws;                                     // N*128 region
  float* z1   = agg1 + (size_t)N * 128;                           // 4096
  float* h    = z1 + 4096;                                        // N*256 region
  float* t    = h + (size_t)N * 256;                              // N*64 region
  float* agg2 = t + (size_t)N * 64;                               // N*64
  uint4* se2  = (uint4*)(agg2 + (size_t)N * 64);                  // E uint4 (32MB)
  int* cnt    = (int*)(se2 + E);                                  // N
  int* rowptr = cnt + N;                                          // N+1
  int* fill   = rowptr + N + 1;                                   // N
  int* bsum   = fill + N;                                         // 256
  int* mode_csr = bsum + 256;                                     // 1 (+pad)
  float* outsorted = (float*)(mode_csr + 4);                      // E
  unsigned short* wh1 = (unsigned short*)(((uintptr_t)(outsorted + E) + 15) & ~(uintptr_t)15);
  unsigned short* wh2 = wh1 + 65536;

  unsigned short* agg1h = (unsigned short*)agg1;                  // N*128
  unsigned short* xh    = agg1h + (size_t)N * 128;                // N*128
  unsigned short* hh    = (unsigned short*)h;                     // N*256
  unsigned short* z2h   = (unsigned short*)t;                     // N*64
  unsigned short* th    = z2h + (size_t)N * 64;                   // N*64

  size_t base = ((size_t)N * 128 + 4096 + (size_t)N * 256 + (size_t)N * 128) * 4;
  size_t need_old = base + 64;
  size_t need_csr = base + (size_t)E * 16 + ((size_t)3 * N + 300) * 4 + (size_t)E * 4
                  + (size_t)(65536 + 32768) * 2 + 128;
  if (ws_size < need_old || out_size < E) return;
  bool use_csr = (ws_size >= need_csr);
  int* mode = use_csr ? mode_csr : (int*)(se2);

  detect_kernel<<<1, 64, 0, stream>>>(ei, mode);

  if (use_csr) {
    zero_kernel<<<17, 256, 0, stream>>>(z1, 4096);
    zero_kernel<<<NB, 256, 0, stream>>>((float*)cnt, N);
    hist_kernel<<<(E + 255) / 256, 256, 0, stream>>>(ei, cnt, mode, E);
    scan1_kernel<<<NB, 256, 0, stream>>>(cnt, rowptr, bsum, N);
    scan2_kernel<<<1, 256, 0, stream>>>(bsum, NB);
    scan3_kernel<<<NB, 256, 0, stream>>>(rowptr, bsum, fill, N, E);
    reorder_kernel<<<(E + 255) / 256, 256, 0, stream>>>(ei, ea, fill, se2, mode, E);
    w16cat_kernel<<<384, 256, 0, stream>>>(Wl1, Wr1, Wl2, Wr2, wh1, wh2);
    long long n4 = (long long)N * 32;
    f32tof16_kernel<<<(int)((n4 + 255) / 256), 256, 0, stream>>>(x, xh, n4);
    agg1_csr_kernel<<<(N + 3) / 4, 256, 0, stream>>>(rowptr, se2, xh, agg1h, N);
    gemm16_kernel<0, 4><<<N / 64, 256, 0, stream>>>((const uint4*)agg1h, (const uint4*)xh, 16,
                                                    wh1, bl1, br1, hh, nullptr);
    gemm16_kernel<1, 2><<<N / 64, 256, 0, stream>>>((const uint4*)hh, (const uint4*)hh, 32,
                                                    wh2, bl2, br2, th, agg2);
    agg2_csr_kernel<<<(N + 3) / 4, 256, 0, stream>>>(rowptr, se2, th, agg2, N);
  } else {
    long long nz = (long long)N * 128 + 4096;
    zero_kernel<<<(int)((nz + 255) / 256), 256, 0, stream>>>(agg1, nz);
    scatter1_kernel<<<E / 4, 256, 0, stream>>>(ei, ea, x, agg1, mode, E);
    gemm_bt<<<dim3(4, N / 64), 256, 0, stream>>>(agg1, Wl1, 128, x, Wr1, 128, bl1, br1, h, 256, 1);
    gemm_bt<<<dim3(1, N / 64), 256, 0, stream>>>(h, Wl2, 256, nullptr, nullptr, 0, nullptr, nullptr, t, 64, 0);
    gemm_bt<<<dim3(1, N / 64), 256, 0, stream>>>(h, Wr2, 256, nullptr, nullptr, 0, bl2, br2, agg2, 64, 0);
    scatter2_kernel<<<E / 4, 256, 0, stream>>>(ei, ea, t, agg2, mode, E);
  }

  fc1_kernel<<<250, 256, 0, stream>>>(agg2, Wfc, bfc, z1);
  fc2_kernel<<<250, 256, 0, stream>>>(z1, Wfc2, bfc2, z2h, N / 64);

  if (use_csr) {
    decoder_kernel<<<2048, 256, 0, stream>>>(se2, ei, z2h, Wd1, bd1, Wd2, bd2,
                                             outsorted, mode, E, 1);
    permute_out<<<(E + 255) / 256, 256, 0, stream>>>(outsorted, se2, out, E);
  } else {
    decoder_kernel<<<2048, 256, 0, stream>>>(se2, ei, z2h, Wd1, bd1, Wd2, bd2,
                                             out, mode, E, 0);
  }
}

// Round 12
// 888.319 us; speedup vs baseline: 1.0936x; 1.0936x over previous
//
#include <hip/hip_runtime.h>
#include <math.h>

typedef __attribute__((ext_vector_type(8))) _Float16 f16x8;
typedef __attribute__((ext_vector_type(4))) _Float16 f16x4;
typedef __attribute__((ext_vector_type(2))) _Float16 f16x2;
typedef __attribute__((ext_vector_type(4))) float f32x4;

static __device__ __forceinline__ int getidx(const int* __restrict__ ei, int mode, long long pos) {
  return mode ? ei[2 * pos] : ei[pos];
}

__global__ void detect_kernel(const int* __restrict__ ei, int* __restrict__ mode) {
  int lane = threadIdx.x & 63;
  int v = ei[2 * lane + 1] | ei[2 * lane + 129];
  unsigned long long nz = __ballot(v != 0);
  if (lane == 0) mode[0] = (nz == 0ull) ? 1 : 0;
}

__global__ void zero_kernel(float* __restrict__ p, long long n) {
  long long i = (long long)blockIdx.x * blockDim.x + threadIdx.x;
  if (i < n) p[i] = 0.f;
}

// ---------- f32 -> f16 conversion (4 elems/thread) ----------
__global__ void f32tof16_kernel(const float* __restrict__ in, unsigned short* __restrict__ out,
                                long long n4) {
  long long i = (long long)blockIdx.x * 256 + threadIdx.x;
  if (i >= n4) return;
  float4 v = ((const float4*)in)[i];
  f16x4 h;
  h[0] = (_Float16)v.x; h[1] = (_Float16)v.y; h[2] = (_Float16)v.z; h[3] = (_Float16)v.w;
  ((f16x4*)out)[i] = h;
}

// ---------- pack conv weights to fp16: Wh1cat[256][256]=[Wl1|Wr1], Wh2cat[128][256]=[Wl2;Wr2] ----------
__global__ void w16cat_kernel(const float* __restrict__ Wl1, const float* __restrict__ Wr1,
                              const float* __restrict__ Wl2, const float* __restrict__ Wr2,
                              unsigned short* __restrict__ wh1, unsigned short* __restrict__ wh2) {
  int idx = blockIdx.x * 256 + threadIdx.x;
  if (idx < 65536) {
    int o = idx >> 8, k = idx & 255;
    float v = (k < 128) ? Wl1[o * 128 + k] : Wr1[o * 128 + k - 128];
    _Float16 hv = (_Float16)v;
    wh1[idx] = *(unsigned short*)&hv;
  } else if (idx < 65536 + 32768) {
    int i2 = idx - 65536;
    int o = i2 >> 8, k = i2 & 255;
    float v = (o < 64) ? Wl2[o * 256 + k] : Wr2[(o - 64) * 256 + k];
    _Float16 hv = (_Float16)v;
    wh2[i2] = *(unsigned short*)&hv;
  }
}

// ================= CSR build (counting sort by dst) =================
__global__ void hist_kernel(const int* __restrict__ ei, int* __restrict__ cnt,
                            const int* __restrict__ modep, int E) {
  const int md = modep[0];
  int e = blockIdx.x * 256 + threadIdx.x;
  if (e >= E) return;
  int d = getidx(ei, md, (long long)E + e);
  atomicAdd(&cnt[d], 1);
}

__global__ void scan1_kernel(const int* __restrict__ cnt, int* __restrict__ pre,
                             int* __restrict__ bsum, int N) {
  __shared__ int ws[4];
  int i = blockIdx.x * 256 + threadIdx.x;
  int v = (i < N) ? cnt[i] : 0;
  int lane = threadIdx.x & 63, w = threadIdx.x >> 6;
  int s = v;
#pragma unroll
  for (int o = 1; o < 64; o <<= 1) { int t = __shfl_up(s, o); if (lane >= o) s += t; }
  if (lane == 63) ws[w] = s;
  __syncthreads();
  int off = 0;
  for (int k = 0; k < w; ++k) off += ws[k];
  if (i < N) pre[i] = s + off - v;
  if (threadIdx.x == 255) bsum[blockIdx.x] = s + off;
}

__global__ void scan2_kernel(int* __restrict__ bsum, int nb) {
  __shared__ int ws[4];
  int i = threadIdx.x;
  int v = (i < nb) ? bsum[i] : 0;
  int lane = i & 63, w = i >> 6;
  int s = v;
#pragma unroll
  for (int o = 1; o < 64; o <<= 1) { int t = __shfl_up(s, o); if (lane >= o) s += t; }
  if (lane == 63) ws[w] = s;
  __syncthreads();
  int off = 0;
  for (int k = 0; k < w; ++k) off += ws[k];
  if (i < nb) bsum[i] = s + off - v;
}

__global__ void scan3_kernel(int* __restrict__ rowptr, const int* __restrict__ bsum,
                             int* __restrict__ fill, int N, int E) {
  int i = blockIdx.x * 256 + threadIdx.x;
  if (i < N) {
    int r = rowptr[i] + bsum[blockIdx.x];
    rowptr[i] = r;
    fill[i] = r;
  }
  if (i == 0) rowptr[N] = E;
}

// reorder: ONE packed 16B scattered store per edge: se2[pos] = (src, w, orig, dst)
__global__ void reorder_kernel(const int* __restrict__ ei, const float* __restrict__ ea,
                               int* __restrict__ fill, uint4* __restrict__ se2,
                               const int* __restrict__ modep, int E) {
  const int md = modep[0];
  int e = blockIdx.x * 256 + threadIdx.x;
  if (e >= E) return;
  int s = getidx(ei, md, e);
  int d = getidx(ei, md, (long long)E + e);
  int pos = atomicAdd(&fill[d], 1);
  se2[pos] = make_uint4((unsigned)s, __float_as_uint(ea[e]), (unsigned)e, (unsigned)d);
}

// ---------- CSR aggregation, conv1: fp16 gather (4-deep MLP), fp32 accum, fp16 store ----------
__global__ void agg1_csr_kernel(const int* __restrict__ rowptr, const uint4* __restrict__ se2,
                                const unsigned short* __restrict__ xh,
                                unsigned short* __restrict__ agg1h, int N) {
  int n = (int)((blockIdx.x * 256 + threadIdx.x) >> 6);
  int lane = threadIdx.x & 63;
  if (n >= N) return;
  int p = rowptr[n], end = rowptr[n + 1];
  float ax = 0.f, ay = 0.f;
  for (; p + 3 < end; p += 4) {
    uint4 e0 = se2[p], e1 = se2[p + 1], e2 = se2[p + 2], e3 = se2[p + 3];
    f16x2 v0 = *(const f16x2*)&xh[(size_t)e0.x * 128 + lane * 2];
    f16x2 v1 = *(const f16x2*)&xh[(size_t)e1.x * 128 + lane * 2];
    f16x2 v2 = *(const f16x2*)&xh[(size_t)e2.x * 128 + lane * 2];
    f16x2 v3 = *(const f16x2*)&xh[(size_t)e3.x * 128 + lane * 2];
    float w0 = __uint_as_float(e0.y), w1 = __uint_as_float(e1.y);
    float w2 = __uint_as_float(e2.y), w3 = __uint_as_float(e3.y);
    ax += (float)v0[0] * w0 + (float)v1[0] * w1 + (float)v2[0] * w2 + (float)v3[0] * w3;
    ay += (float)v0[1] * w0 + (float)v1[1] * w1 + (float)v2[1] * w2 + (float)v3[1] * w3;
  }
  for (; p < end; ++p) {
    uint4 e0 = se2[p];
    float w0 = __uint_as_float(e0.y);
    f16x2 v0 = *(const f16x2*)&xh[(size_t)e0.x * 128 + lane * 2];
    ax += (float)v0[0] * w0;
    ay += (float)v0[1] * w0;
  }
  f16x2 st; st[0] = (_Float16)ax; st[1] = (_Float16)ay;
  *(f16x2*)&agg1h[(size_t)n * 128 + lane * 2] = st;
}

// ---------- CSR aggregation, conv2: fp16 gather (4-deep MLP) ----------
__global__ void agg2_csr_kernel(const int* __restrict__ rowptr, const uint4* __restrict__ se2,
                                const unsigned short* __restrict__ th, float* __restrict__ agg2,
                                int N) {
  int n = (int)((blockIdx.x * 256 + threadIdx.x) >> 6);
  int lane = threadIdx.x & 63;
  if (n >= N) return;
  int p = rowptr[n], end = rowptr[n + 1];
  float acc = 0.f;
  for (; p + 3 < end; p += 4) {
    uint4 e0 = se2[p], e1 = se2[p + 1], e2 = se2[p + 2], e3 = se2[p + 3];
    _Float16 t0 = *(const _Float16*)&th[(size_t)e0.x * 64 + lane];
    _Float16 t1 = *(const _Float16*)&th[(size_t)e1.x * 64 + lane];
    _Float16 t2 = *(const _Float16*)&th[(size_t)e2.x * 64 + lane];
    _Float16 t3 = *(const _Float16*)&th[(size_t)e3.x * 64 + lane];
    acc += (float)t0 * __uint_as_float(e0.y) + (float)t1 * __uint_as_float(e1.y)
         + (float)t2 * __uint_as_float(e2.y) + (float)t3 * __uint_as_float(e3.y);
  }
  for (; p < end; ++p) {
    uint4 e0 = se2[p];
    _Float16 t0 = *(const _Float16*)&th[(size_t)e0.x * 64 + lane];
    acc += (float)t0 * __uint_as_float(e0.y);
  }
  agg2[(size_t)n * 64 + lane] += acc;
}

// ================= fallback atomic scatters (fp32 inputs) =================
__global__ void scatter1_kernel(const int* __restrict__ ei, const float* __restrict__ ea,
                                const float* __restrict__ x, float* __restrict__ agg1,
                                const int* __restrict__ modep, int E) {
  const int md = modep[0];
  int e = (int)(((long long)blockIdx.x * 256 + threadIdx.x) >> 6);
  int lane = threadIdx.x & 63;
  if (e >= E) return;
  int s = getidx(ei, md, e);
  int d = getidx(ei, md, (long long)E + e);
  float w = ea[e];
  float2 v = *(const float2*)&x[(size_t)s * 128 + lane * 2];
  float* ap = &agg1[(size_t)d * 128 + lane * 2];
  atomicAdd(ap, v.x * w);
  atomicAdd(ap + 1, v.y * w);
}

__global__ void scatter2_kernel(const int* __restrict__ ei, const float* __restrict__ ea,
                                const float* __restrict__ t, float* __restrict__ agg2,
                                const int* __restrict__ modep, int E) {
  const int md = modep[0];
  int e = (int)(((long long)blockIdx.x * 256 + threadIdx.x) >> 6);
  int lane = threadIdx.x & 63;
  if (e >= E) return;
  int s = getidx(ei, md, e);
  int d = getidx(ei, md, (long long)E + e);
  float w = ea[e];
  atomicAdd(&agg2[(size_t)d * 64 + lane], t[(size_t)s * 64 + lane] * w);
}

// ---------- generic fp32 GEMM (fallback path only) ----------
__global__ void gemm_bt(const float* __restrict__ A1, const float* __restrict__ W1, int K1,
                        const float* __restrict__ A2, const float* __restrict__ W2, int K2,
                        const float* __restrict__ b1, const float* __restrict__ b2,
                        float* __restrict__ C, int NC, int doRelu) {
  __shared__ float As[64][17];
  __shared__ float Ws[64][17];
  int tid = threadIdx.x;
  int tx = tid & 15, ty = tid >> 4;
  int row0 = blockIdx.y * 64, col0 = blockIdx.x * 64;
  float acc[4][4] = {};
  for (int srcsel = 0; srcsel < 2; ++srcsel) {
    const float* A = srcsel ? A2 : A1;
    const float* W = srcsel ? W2 : W1;
    int K = srcsel ? K2 : K1;
    if (!A) continue;
    for (int kb = 0; kb < K; kb += 16) {
#pragma unroll
      for (int i = 0; i < 4; ++i) {
        int idx = tid + 256 * i;
        int r = idx >> 4, k = idx & 15;
        As[r][k] = A[(size_t)(row0 + r) * K + kb + k];
        Ws[r][k] = W[(size_t)(col0 + r) * K + kb + k];
      }
      __syncthreads();
#pragma unroll
      for (int k = 0; k < 16; ++k) {
        float a[4], w[4];
#pragma unroll
        for (int i = 0; i < 4; ++i) a[i] = As[ty * 4 + i][k];
#pragma unroll
        for (int j = 0; j < 4; ++j) w[j] = Ws[tx * 4 + j][k];
#pragma unroll
        for (int i = 0; i < 4; ++i)
#pragma unroll
          for (int j = 0; j < 4; ++j) acc[i][j] += a[i] * w[j];
      }
      __syncthreads();
    }
  }
#pragma unroll
  for (int j = 0; j < 4; ++j) {
    int c = col0 + tx * 4 + j;
    float bias = (b1 ? b1[c] : 0.f) + (b2 ? b2[c] : 0.f);
#pragma unroll
    for (int i = 0; i < 4; ++i) {
      float v = acc[i][j] + bias;
      if (doRelu) v = fmaxf(v, 0.f);
      C[(size_t)(row0 + ty * 4 + i) * NC + c] = v;
    }
  }
}

// ---------- fp16 MFMA GEMM, M-tile 64, 4 waves ----------
template <int MODE, int OTN>
__global__ void __launch_bounds__(256, 2)
gemm16_kernel(const uint4* __restrict__ A0, const uint4* __restrict__ A1, int c0,
              const unsigned short* __restrict__ Wcat,
              const float* __restrict__ b1, const float* __restrict__ b2,
              unsigned short* __restrict__ outH, float* __restrict__ outF) {
  __shared__ uint4 At[64 * 33];   // 33.8 KB
  int tid = threadIdx.x;
  int lane = tid & 63;
  int wv = tid >> 6;
  int l15 = lane & 15, g = lane >> 4;
  int row0 = blockIdx.x * 64;

  f16x8 bfr[OTN][8];
  float biasv[OTN];
#pragma unroll
  for (int ot = 0; ot < OTN; ++ot) {
    int o = wv * (OTN * 16) + ot * 16 + l15;
    if (MODE == 0) biasv[ot] = b1[o] + b2[o];
    else biasv[ot] = (o >= 64) ? (b1[o - 64] + b2[o - 64]) : 0.f;
#pragma unroll
    for (int kb = 0; kb < 8; ++kb)
      bfr[ot][kb] = *(const f16x8*)&Wcat[(size_t)o * 256 + kb * 32 + g * 8];
  }

#pragma unroll
  for (int i = 0; i < 8; ++i) {
    int idx = tid + 256 * i;
    int r = idx >> 5, c = idx & 31;
    uint4 v = (c < c0) ? A0[(size_t)(row0 + r) * c0 + c]
                       : A1[(size_t)(row0 + r) * (32 - c0) + (c - c0)];
    At[r * 33 + c] = v;
  }
  __syncthreads();

#pragma unroll
  for (int est = 0; est < 4; ++est) {
    int rowA = est * 16 + l15;
    f16x8 a[8];
#pragma unroll
    for (int kb = 0; kb < 8; ++kb)
      a[kb] = *(const f16x8*)&At[rowA * 33 + kb * 4 + g];
#pragma unroll
    for (int ot = 0; ot < OTN; ++ot) {
      f32x4 acc = {0.f, 0.f, 0.f, 0.f};
#pragma unroll
      for (int kb = 0; kb < 8; ++kb)
        acc = __builtin_amdgcn_mfma_f32_16x16x32_f16(a[kb], bfr[ot][kb], acc, 0, 0, 0);
      int o = wv * (OTN * 16) + ot * 16 + l15;
#pragma unroll
      for (int r = 0; r < 4; ++r) {
        int row = row0 + est * 16 + g * 4 + r;
        float v = acc[r] + biasv[ot];
        if (MODE == 0) {
          _Float16 hv = (_Float16)fmaxf(v, 0.f);
          outH[(size_t)row * 256 + o] = *(unsigned short*)&hv;
        } else {
          if (o < 64) {
            _Float16 hv = (_Float16)v;
            outH[(size_t)row * 64 + o] = *(unsigned short*)&hv;
          } else {
            outF[(size_t)row * 64 + (o - 64)] = v;
          }
        }
      }
    }
  }
}

// ---------- fc1 ----------
__global__ void __launch_bounds__(256) fc1_kernel(const float* __restrict__ z0,
                                                  const float* __restrict__ Wfc,
                                                  const float* __restrict__ bfc,
                                                  float* __restrict__ z1) {
  __shared__ float Zs[64][260];
  int tid = threadIdx.x;
  int kc = blockIdx.x;
  const size_t kbase = (size_t)kc * 256;
  for (int i = tid; i < 64 * 256; i += 256) {
    int b = i >> 8, k = i & 255;
    Zs[b][k] = fmaxf(z0[(size_t)b * 64000 + kbase + k], 0.f);
  }
  __syncthreads();
  int o = tid >> 2, q = tid & 3;
  float acc[16];
#pragma unroll
  for (int j = 0; j < 16; ++j) acc[j] = 0.f;
  const float* wp = Wfc + (size_t)o * 64000 + kbase;
  for (int k = 0; k < 256; k += 4) {
    float4 w = *(const float4*)&wp[k];
#pragma unroll
    for (int j = 0; j < 16; ++j) {
      float4 z = *(const float4*)&Zs[q * 16 + j][k];
      acc[j] += z.x * w.x + z.y * w.y + z.z * w.z + z.w * w.w;
    }
  }
  float bias = (kc == 0) ? bfc[o] : 0.f;
#pragma unroll
  for (int j = 0; j < 16; ++j)
    atomicAdd(&z1[(q * 16 + j) * 64 + o], acc[j] + bias);
}

// ---------- fc2: z2 packed per node as fp16: [node][0..63] ----------
__global__ void fc2_kernel(const float* __restrict__ z1, const float* __restrict__ Wfc2,
                           const float* __restrict__ bfc2,
                           unsigned short* __restrict__ z2h, int nPerB) {
  __shared__ float z1s[4096];
  __shared__ float Ws[256][65];
  int tid = threadIdx.x;
  for (int i = tid; i < 4096; i += 256) z1s[i] = z1[i];
  int m0 = blockIdx.x * 256;
  for (int i = tid; i < 256 * 64; i += 256) {
    int r = i >> 6, j = i & 63;
    Ws[r][j] = Wfc2[(size_t)(m0 + r) * 64 + j];
  }
  __syncthreads();
  int m = m0 + tid;
  float bias = bfc2[m];
  int ninb = m >> 6, feat = m & 63;
  for (int b = 0; b < 64; ++b) {
    float acc = bias;
#pragma unroll
    for (int j = 0; j < 64; ++j) acc += z1s[b * 64 + j] * Ws[tid][j];
    float v = fmaxf(acc, 0.f);
    _Float16 hv = (_Float16)v;   // RNE
    size_t node = (size_t)b * nPerB + ninb;
    z2h[node * 64 + feat] = *(unsigned short*)&hv;
  }
}

// ---------- decoder: fp16 MFMA, coalesced gather, packed se2 (r10 version) ----------
__global__ void __launch_bounds__(256, 2)
decoder_kernel(const uint4* __restrict__ se2, const int* __restrict__ ei,
               const unsigned short* __restrict__ z2h,
               const float* __restrict__ Wd1, const float* __restrict__ bd1,
               const float* __restrict__ Wd2, const float* __restrict__ bd2,
               float* __restrict__ obuf, const int* __restrict__ modep,
               int E, int sorted) {
  __shared__ uint4 At[128 * 17];     // 34.8 KB
  __shared__ int nid[256];
  __shared__ float red[4][128];
  const int md = modep[0];
  int tid = threadIdx.x;
  int lane = tid & 63;
  int wv = tid >> 6;
  int l15 = lane & 15, g = lane >> 4;
  int ue = tid >> 3, c8 = tid & 7;

  f16x8 bfr[4][4];
  float wd2v[4], bd1v[4];
#pragma unroll
  for (int ot = 0; ot < 4; ++ot) {
    int o = wv * 64 + ot * 16 + l15;
    wd2v[ot] = Wd2[o];
    bd1v[ot] = bd1[o];
#pragma unroll
    for (int kb = 0; kb < 4; ++kb) {
      const float* wp = Wd1 + (size_t)o * 128 + kb * 32 + g * 8;
      f16x8 bh;
#pragma unroll
      for (int q = 0; q < 8; ++q) bh[q] = (_Float16)wp[q];
      bfr[ot][kb] = bh;
    }
  }
  float bd2v = bd2[0];

  int ntiles = E >> 7;
  int tpb = (ntiles + gridDim.x - 1) / gridDim.x;
  int tA = blockIdx.x * tpb;
  int tB = min(tA + tpb, ntiles);

  for (int tile = tA; tile < tB; ++tile) {
    long long ebase = (long long)tile << 7;
    if (sorted) {
      if (tid < 128) {
        uint4 v = se2[ebase + tid];
        nid[tid] = (int)v.x;
        nid[128 + tid] = (int)v.w;
      }
    } else {
      long long p = ebase + (tid & 127);
      nid[tid] = getidx(ei, md, (tid < 128) ? p : (long long)E + p);
    }
    __syncthreads();
#pragma unroll
    for (int pass = 0; pass < 8; ++pass) {
      int u = pass * 32 + ue;
      int node = nid[u];
      uint4 v = *((const uint4*)(z2h + (size_t)node * 64) + c8);
      int eRow = u & 127, side = u >> 7;
      At[eRow * 17 + side * 8 + c8] = v;
    }
    __syncthreads();

    float sacc[8][4];
#pragma unroll
    for (int i = 0; i < 8; ++i)
#pragma unroll
      for (int r = 0; r < 4; ++r) sacc[i][r] = 0.f;

#pragma unroll
    for (int est = 0; est < 8; ++est) {
      int row = est * 16 + l15;
      f16x8 a[4];
#pragma unroll
      for (int kb = 0; kb < 4; ++kb)
        a[kb] = *(const f16x8*)&At[row * 17 + kb * 4 + g];
#pragma unroll
      for (int ot = 0; ot < 4; ++ot) {
        f32x4 acc = {0.f, 0.f, 0.f, 0.f};
#pragma unroll
        for (int kb = 0; kb < 4; ++kb)
          acc = __builtin_amdgcn_mfma_f32_16x16x32_f16(a[kb], bfr[ot][kb], acc, 0, 0, 0);
#pragma unroll
        for (int r = 0; r < 4; ++r) {
          float pp = fmaxf(acc[r] + bd1v[ot], 0.f);
          sacc[est][r] += pp * wd2v[ot];
        }
      }
    }
#pragma unroll
    for (int est = 0; est < 8; ++est)
#pragma unroll
      for (int r = 0; r < 4; ++r) {
        float s = sacc[est][r];
        s += __shfl_xor(s, 1); s += __shfl_xor(s, 2);
        s += __shfl_xor(s, 4); s += __shfl_xor(s, 8);
        sacc[est][r] = s;
      }
    if (l15 == 0) {
#pragma unroll
      for (int est = 0; est < 8; ++est)
#pragma unroll
        for (int r = 0; r < 4; ++r)
          red[wv][est * 16 + g * 4 + r] = sacc[est][r];
    }
    __syncthreads();
    if (tid < 128) {
      float s = red[0][tid] + red[1][tid] + red[2][tid] + red[3][tid] + bd2v;
      obuf[ebase + tid] = 1.f / (1.f + __expf(-s));
    }
  }
}

__global__ void permute_out(const float* __restrict__ outsorted, const uint4* __restrict__ se2,
                            float* __restrict__ out, int E) {
  int i = blockIdx.x * 256 + threadIdx.x;
  if (i < E) out[se2[i].z] = outsorted[i];
}

extern "C" void kernel_launch(void* const* d_in, const int* in_sizes, int n_in,
                              void* d_out, int out_size, void* d_ws, size_t ws_size,
                              hipStream_t stream) {
  const float* x    = (const float*)d_in[0];
  const int*   ei   = (const int*)d_in[1];
  const float* ea   = (const float*)d_in[2];
  const float* Wl1  = (const float*)d_in[3];
  const float* bl1  = (const float*)d_in[4];
  const float* Wr1  = (const float*)d_in[5];
  const float* br1  = (const float*)d_in[6];
  const float* Wl2  = (const float*)d_in[7];
  const float* bl2  = (const float*)d_in[8];
  const float* Wr2  = (const float*)d_in[9];
  const float* br2  = (const float*)d_in[10];
  const float* Wfc  = (const float*)d_in[11];
  const float* bfc  = (const float*)d_in[12];
  const float* Wfc2 = (const float*)d_in[13];
  const float* bfc2 = (const float*)d_in[14];
  const float* Wd1  = (const float*)d_in[15];
  const float* bd1  = (const float*)d_in[16];
  const float* Wd2  = (const float*)d_in[17];
  const float* bd2  = (const float*)d_in[18];
  float* out = (float*)d_out;

  const int N = in_sizes[0] / 128;   // 64000
  const int E = in_sizes[2];         // 2048000
  const int NB = (N + 255) / 256;

  float* agg1 = (float*)d_ws;                                     // N*128 region
  float* z1   = agg1 + (size_t)N * 128;                           // 4096
  float* h    = z1 + 4096;                                        // N*256 region
  float* t    = h + (size_t)N * 256;                              // N*64 region
  float* agg2 = t + (size_t)N * 64;                               // N*64
  uint4* se2  = (uint4*)(agg2 + (size_t)N * 64);                  // E uint4 (32MB)
  int* cnt    = (int*)(se2 + E);                                  // N
  int* rowptr = cnt + N;                                          // N+1
  int* fill   = rowptr + N + 1;                                   // N
  int* bsum   = fill + N;                                         // 256
  int* mode_csr = bsum + 256;                                     // 1 (+pad)
  float* outsorted = (float*)(mode_csr + 4);                      // E
  unsigned short* wh1 = (unsigned short*)(((uintptr_t)(outsorted + E) + 15) & ~(uintptr_t)15);
  unsigned short* wh2 = wh1 + 65536;

  unsigned short* agg1h = (unsigned short*)agg1;                  // N*128
  unsigned short* xh    = agg1h + (size_t)N * 128;                // N*128
  unsigned short* hh    = (unsigned short*)h;                     // N*256
  unsigned short* z2h   = (unsigned short*)t;                     // N*64
  unsigned short* th    = z2h + (size_t)N * 64;                   // N*64

  size_t base = ((size_t)N * 128 + 4096 + (size_t)N * 256 + (size_t)N * 128) * 4;
  size_t need_old = base + 64;
  size_t need_csr = base + (size_t)E * 16 + ((size_t)3 * N + 300) * 4 + (size_t)E * 4
                  + (size_t)(65536 + 32768) * 2 + 128;
  if (ws_size < need_old || out_size < E) return;
  bool use_csr = (ws_size >= need_csr);
  int* mode = use_csr ? mode_csr : (int*)(se2);

  detect_kernel<<<1, 64, 0, stream>>>(ei, mode);

  if (use_csr) {
    zero_kernel<<<17, 256, 0, stream>>>(z1, 4096);
    zero_kernel<<<NB, 256, 0, stream>>>((float*)cnt, N);
    hist_kernel<<<(E + 255) / 256, 256, 0, stream>>>(ei, cnt, mode, E);
    scan1_kernel<<<NB, 256, 0, stream>>>(cnt, rowptr, bsum, N);
    scan2_kernel<<<1, 256, 0, stream>>>(bsum, NB);
    scan3_kernel<<<NB, 256, 0, stream>>>(rowptr, bsum, fill, N, E);
    reorder_kernel<<<(E + 255) / 256, 256, 0, stream>>>(ei, ea, fill, se2, mode, E);
    w16cat_kernel<<<384, 256, 0, stream>>>(Wl1, Wr1, Wl2, Wr2, wh1, wh2);
    long long n4 = (long long)N * 32;
    f32tof16_kernel<<<(int)((n4 + 255) / 256), 256, 0, stream>>>(x, xh, n4);
    agg1_csr_kernel<<<(N + 3) / 4, 256, 0, stream>>>(rowptr, se2, xh, agg1h, N);
    gemm16_kernel<0, 4><<<N / 64, 256, 0, stream>>>((const uint4*)agg1h, (const uint4*)xh, 16,
                                                    wh1, bl1, br1, hh, nullptr);
    gemm16_kernel<1, 2><<<N / 64, 256, 0, stream>>>((const uint4*)hh, (const uint4*)hh, 32,
                                                    wh2, bl2, br2, th, agg2);
    agg2_csr_kernel<<<(N + 3) / 4, 256, 0, stream>>>(rowptr, se2, th, agg2, N);
  } else {
    long long nz = (long long)N * 128 + 4096;
    zero_kernel<<<(int)((nz + 255) / 256), 256, 0, stream>>>(agg1, nz);
    scatter1_kernel<<<E / 4, 256, 0, stream>>>(ei, ea, x, agg1, mode, E);
    gemm_bt<<<dim3(4, N / 64), 256, 0, stream>>>(agg1, Wl1, 128, x, Wr1, 128, bl1, br1, h, 256, 1);
    gemm_bt<<<dim3(1, N / 64), 256, 0, stream>>>(h, Wl2, 256, nullptr, nullptr, 0, nullptr, nullptr, t, 64, 0);
    gemm_bt<<<dim3(1, N / 64), 256, 0, stream>>>(h, Wr2, 256, nullptr, nullptr, 0, bl2, br2, agg2, 64, 0);
    scatter2_kernel<<<E / 4, 256, 0, stream>>>(ei, ea, t, agg2, mode, E);
  }

  fc1_kernel<<<250, 256, 0, stream>>>(agg2, Wfc, bfc, z1);
  fc2_kernel<<<250, 256, 0, stream>>>(z1, Wfc2, bfc2, z2h, N / 64);

  if (use_csr) {
    decoder_kernel<<<2048, 256, 0, stream>>>(se2, ei, z2h, Wd1, bd1, Wd2, bd2,
                                             outsorted, mode, E, 1);
    permute_out<<<(E + 255) / 256, 256, 0, stream>>>(outsorted, se2, out, E);
  } else {
    decoder_kernel<<<2048, 256, 0, stream>>>(se2, ei, z2h, Wd1, bd1, Wd2, bd2,
                                             out, mode, E, 0);
  }
}